// Round 6
// baseline (1742.287 us; speedup 1.0000x reference)
//
#include <hip/hip_runtime.h>
#include <hip/hip_fp16.h>
#include <cstdint>

typedef _Float16 h2 __attribute__((ext_vector_type(2)));
typedef _Float16 h8 __attribute__((ext_vector_type(8)));
typedef float    f4 __attribute__((ext_vector_type(4)));
typedef uint32_t u4 __attribute__((ext_vector_type(4)));

#define BATCH 64
#define TSTEPS 1024
#define DDIM 512
#define HDIM 512

static __device__ __forceinline__ float fdot2(uint32_t w, uint32_t h, float acc) {
  return __builtin_amdgcn_fdot2(__builtin_bit_cast(h2, w), __builtin_bit_cast(h2, h), acc, false);
}

// Raw barrier: LDS-ordering only — NO vmcnt drain (xp loads / out stores stay
// in flight across barriers; no cross-wave vmem deps). Verified win in r4.
#define BAR_LDS()                                            \
  do {                                                       \
    __builtin_amdgcn_sched_barrier(0);                       \
    asm volatile("s_waitcnt lgkmcnt(0)" ::: "memory");       \
    __builtin_amdgcn_s_barrier();                            \
    __builtin_amdgcn_sched_barrier(0);                       \
  } while (0)

// ---------------------------------------------------------------------------
// prep: f16 weight conversion, pair-transposed Whh, bias sums.
// ---------------------------------------------------------------------------
__global__ void prep_kernel(const float* __restrict__ Wih_f, const float* __restrict__ Whh_f,
                            const float* __restrict__ bih_f, const float* __restrict__ bhh_f,
                            const float* __restrict__ Wih_b, const float* __restrict__ Whh_b,
                            const float* __restrict__ bih_b, const float* __restrict__ bhh_b,
                            _Float16* __restrict__ wi16, uint32_t* __restrict__ whT,
                            float* __restrict__ bsum) {
  int i = blockIdx.x * 256 + threadIdx.x;
  if (i < 2 * 512 * 512) {
    const float* s = (i < 512 * 512) ? Wih_f : Wih_b;
    wi16[i] = (_Float16)s[i & (512 * 512 - 1)];
  }
  if (i < 2 * 256 * 512) {
    int d = i >> 17; int rem = i & ((1 << 17) - 1);
    int kp = rem >> 9; int j = rem & 511;
    const float* W = d ? Whh_b : Whh_f;
    h2 p; p[0] = (_Float16)W[j * 512 + 2 * kp]; p[1] = (_Float16)W[j * 512 + 2 * kp + 1];
    whT[i] = __builtin_bit_cast(uint32_t, p);
  }
  if (i < 2 * 512) {
    int d = i >> 9, j = i & 511;
    bsum[i] = d ? (bih_b[j] + bhh_b[j]) : (bih_f[j] + bhh_f[j]);
  }
}

// ---------------------------------------------------------------------------
// xp_gemm (unchanged): xp[dir][m][n] f16, m = b*1024 + t (processing order).
// ---------------------------------------------------------------------------
__global__ __launch_bounds__(256) void xp_gemm(const float* __restrict__ x,
                                               const _Float16* __restrict__ wi,
                                               const float* __restrict__ bsum,
                                               _Float16* __restrict__ xp) {
  __shared__ _Float16 As[128][40];
  __shared__ _Float16 Bs[128][40];
  const int mt = blockIdx.x, nt = blockIdx.y, dir = blockIdx.z;
  const int m0 = mt * 128, n0 = nt * 128;
  const int tid = threadIdx.x;
  const int lane = tid & 63, w = tid >> 6;
  const int wr = w >> 1, wc = w & 1;
  const int ra = tid >> 1, hf = tid & 1;

  const int mrow = m0 + ra;
  const int bb = mrow >> 10, pp = mrow & 1023;
  const int srow = dir ? ((bb << 10) + (1023 - pp)) : mrow;
  const float*    xbase = x + (size_t)srow * 512 + hf * 16;
  const _Float16* wbase = wi + (size_t)dir * 512 * 512 + (size_t)(n0 + ra) * 512 + hf * 16;

  f4 acc[4][4];
  #pragma unroll
  for (int a = 0; a < 4; ++a)
    #pragma unroll
    for (int b = 0; b < 4; ++b) acc[a][b] = (f4)0.f;

  for (int k0 = 0; k0 < 512; k0 += 32) {
    f4 x0 = *(const f4*)(xbase + k0);
    f4 x1 = *(const f4*)(xbase + k0 + 4);
    f4 x2 = *(const f4*)(xbase + k0 + 8);
    f4 x3 = *(const f4*)(xbase + k0 + 12);
    h8 b0 = *(const h8*)(wbase + k0);
    h8 b1 = *(const h8*)(wbase + k0 + 8);
    h8 a0, a1;
    #pragma unroll
    for (int u = 0; u < 4; ++u) {
      a0[u] = (_Float16)x0[u]; a0[4 + u] = (_Float16)x1[u];
      a1[u] = (_Float16)x2[u]; a1[4 + u] = (_Float16)x3[u];
    }
    __syncthreads();
    *(h8*)&As[ra][hf * 16]     = a0;
    *(h8*)&As[ra][hf * 16 + 8] = a1;
    *(h8*)&Bs[ra][hf * 16]     = b0;
    *(h8*)&Bs[ra][hf * 16 + 8] = b1;
    __syncthreads();
    h8 af[4], bf[4];
    #pragma unroll
    for (int fm = 0; fm < 4; ++fm)
      af[fm] = *(const h8*)&As[wr * 64 + fm * 16 + (lane & 15)][(lane >> 4) * 8];
    #pragma unroll
    for (int fn = 0; fn < 4; ++fn)
      bf[fn] = *(const h8*)&Bs[wc * 64 + fn * 16 + (lane & 15)][(lane >> 4) * 8];
    #pragma unroll
    for (int fm = 0; fm < 4; ++fm)
      #pragma unroll
      for (int fn = 0; fn < 4; ++fn)
        acc[fm][fn] = __builtin_amdgcn_mfma_f32_16x16x32_f16(af[fm], bf[fn], acc[fm][fn], 0, 0, 0);
  }

  float bsv[4];
  #pragma unroll
  for (int fn = 0; fn < 4; ++fn)
    bsv[fn] = bsum[dir * 512 + n0 + wc * 64 + fn * 16 + (lane & 15)];
  #pragma unroll
  for (int fm = 0; fm < 4; ++fm)
    #pragma unroll
    for (int fn = 0; fn < 4; ++fn)
      #pragma unroll
      for (int u = 0; u < 4; ++u) {
        int m = m0 + wr * 64 + fm * 16 + (lane >> 4) * 4 + u;
        int n = n0 + wc * 64 + fn * 16 + (lane & 15);
        xp[((size_t)dir << 25) + (size_t)m * 512 + n] = (_Float16)(acc[fm][fn][u] + bsv[fn]);
      }
}

// ---------------------------------------------------------------------------
// rnn_rec (r6): k-eighth wave mapping, h via SGPR broadcast.
//   wave w: ke = w>>1 (k-eighth: pairs ke*32..ke*32+31), jh = w&1.
//   lane lv = l&63 owns j = jh*256 + lv*4 + {0..3} (4 accumulators).
//   Weights per lane: 32 pairs x 4 j = 128 u32: 24 pairs (96 u32) in regs as
//   u4-per-pair, 8 pairs in LDS (group-contiguous, b128 reads, conflict-free).
//   h per step: ONE lane-distributed ds_read_b32 (lane p holds pair ke*32+p,
//   2-way broadcast aliasing = free), then 32 v_readlane -> SGPRs; fdot2
//   sources h from SGPR (VOP3P allows 1 SGPR operand).
//   This removes the 256 uniform-b128 h-broadcasts (the 6.7e7 conflict term
//   and ~1024 LDS cyc/step) from the LDS pipe.
// ---------------------------------------------------------------------------
__global__ __launch_bounds__(1024, 4) void rnn_rec(const _Float16* __restrict__ xp,
                                                   const uint32_t* __restrict__ whT,
                                                   float* __restrict__ out) {
  extern __shared__ char smem[];
  uint32_t* wl   = (uint32_t*)smem;              // 128 KB, group-contiguous
  uint32_t* hl   = (uint32_t*)(smem + 131072);   // h(t): 256 f16x2 pairs
  float*    psum = (float*)(smem + 132096);      // [8][512] = 16 KB

  const int bid = blockIdx.x;
  const int dir = bid & 1, b = bid >> 1;
  const int l = threadIdx.x;
  const int w = l >> 6, lv = l & 63;
  const int ke = w >> 1, jh = w & 1;
  const int jbase = jh * 256 + lv * 4;

  // ---- weights: pairs P = ke*32+p, j = jbase..jbase+3 (u4 per pair) ----
  const uint32_t* wb = whT + dir * (256 * 512) + (ke * 32) * 512 + jbase;
  u4 wr_[24];
  #pragma unroll
  for (int p = 0; p < 24; ++p) wr_[p] = *(const u4*)(wb + p * 512);

  // LDS pairs p=24..31: group-contiguous slot = (l>>3)*1024 + g*128 + (l&7)*16
  char* wlb = (char*)wl + (l >> 3) * 1024 + (l & 7) * 16;
  #pragma unroll
  for (int g = 0; g < 8; ++g)
    *(u4*)(wlb + g * 128) = *(const u4*)(wb + (24 + g) * 512);

  if (l < 256) hl[l] = 0;
  __syncthreads();

  const _Float16* xpp = xp + ((size_t)dir << 25) + ((size_t)b << 19);
  float* op = out + (((size_t)(b * 2 + dir)) << 19);

  for (int t = 0; t < TSTEPS; ++t) {
    // xp prefetch: consumed in epilogue; never drained at a barrier.
    float xpv = 0.f;
    if (l < 512) xpv = (float)xpp[(size_t)t * 512 + l];

    // ---- h fetch: 1 lane-distributed read + 32 readlane -> SGPRs ----
    uint32_t hvl = hl[ke * 32 + (lv & 31)];      // lane p (and p+32) holds pair ke*32+p
    uint32_t hs[32];
    #pragma unroll
    for (int p = 0; p < 32; ++p) hs[p] = __builtin_amdgcn_readlane(hvl, p);

    f4 acc = (f4)0.f;
    #pragma unroll
    for (int p = 0; p < 24; ++p) {
      #pragma unroll
      for (int i = 0; i < 4; ++i) acc[i] = fdot2(wr_[p][i], hs[p], acc[i]);
    }
    #pragma unroll
    for (int g = 0; g < 8; ++g) {
      u4 wv = *(const u4*)(wlb + g * 128);       // b128, conflict-free
      #pragma unroll
      for (int i = 0; i < 4; ++i) acc[i] = fdot2(wv[i], hs[24 + g], acc[i]);
    }
    *(f4*)&psum[ke * 512 + jbase] = acc;         // b128, lanes 16B apart: free
    BAR_LDS();                                    // B1 (no vmcnt drain)

    if (l < 512) {
      float s0 = psum[l]          + psum[512 + l];
      float s1 = psum[1024 + l]   + psum[1536 + l];
      float s2 = psum[2048 + l]   + psum[2560 + l];
      float s3 = psum[3072 + l]   + psum[3584 + l];
      float s = ((s0 + s1) + (s2 + s3)) + xpv;
      float e = __expf(2.f * s);
      float hv = 1.f - 2.f * __builtin_amdgcn_rcpf(e + 1.f);   // tanh(s)
      op[(size_t)t * 512 + l] = hv;              // fire-and-forget store
      ((_Float16*)hl)[l] = (_Float16)hv;
    }
    BAR_LDS();                                    // B2: h(t) ready in LDS
  }
}

// ---------------------------------------------------------------------------
extern "C" void kernel_launch(void* const* d_in, const int* in_sizes, int n_in,
                              void* d_out, int out_size, void* d_ws, size_t ws_size,
                              hipStream_t stream) {
  const float* x     = (const float*)d_in[0];
  const float* Wih_f = (const float*)d_in[1];
  const float* Whh_f = (const float*)d_in[2];
  const float* bih_f = (const float*)d_in[3];
  const float* bhh_f = (const float*)d_in[4];
  const float* Wih_b = (const float*)d_in[5];
  const float* Whh_b = (const float*)d_in[6];
  const float* bih_b = (const float*)d_in[7];
  const float* bhh_b = (const float*)d_in[8];

  char* ws = (char*)d_ws;
  _Float16* xp16 = (_Float16*)ws;                 // 128 MB
  _Float16* wi16 = (_Float16*)(ws + 134217728);   // 1 MB
  uint32_t* whT  = (uint32_t*)(ws + 135266304);   // 1 MB
  float*    bsum = (float*)(ws + 136314880);      // 4 KB
  float* out = (float*)d_out;

  prep_kernel<<<2048, 256, 0, stream>>>(Wih_f, Whh_f, bih_f, bhh_f,
                                        Wih_b, Whh_b, bih_b, bhh_b, wi16, whT, bsum);
  dim3 g(512, 4, 2);
  xp_gemm<<<g, 256, 0, stream>>>(x, wi16, bsum, xp16);

  const int REC_LDS = 148480;  // 128K wl + 1K hl + 16K psum
  hipFuncSetAttribute((const void*)rnn_rec, hipFuncAttributeMaxDynamicSharedMemorySize, REC_LDS);
  rnn_rec<<<128, 1024, REC_LDS, stream>>>(xp16, whT, out);
}

// Round 7
// 1566.173 us; speedup vs baseline: 1.1124x; 1.1124x over previous
//
#include <hip/hip_runtime.h>
#include <hip/hip_fp16.h>
#include <cstdint>

typedef _Float16 h2 __attribute__((ext_vector_type(2)));
typedef _Float16 h8 __attribute__((ext_vector_type(8)));
typedef float    f2 __attribute__((ext_vector_type(2)));
typedef float    f4 __attribute__((ext_vector_type(4)));
typedef uint32_t u4 __attribute__((ext_vector_type(4)));

#define BATCH 64
#define TSTEPS 1024
#define DDIM 512
#define HDIM 512

static __device__ __forceinline__ float fdot2(uint32_t w, uint32_t h, float acc) {
  return __builtin_amdgcn_fdot2(__builtin_bit_cast(h2, w), __builtin_bit_cast(h2, h), acc, false);
}

// Raw barrier: LDS-ordering only — NO vmcnt drain (xp loads / out stores stay
// in flight across barriers; no cross-wave vmem deps). Verified win in r4.
#define BAR_LDS()                                            \
  do {                                                       \
    __builtin_amdgcn_sched_barrier(0);                       \
    asm volatile("s_waitcnt lgkmcnt(0)" ::: "memory");       \
    __builtin_amdgcn_s_barrier();                            \
    __builtin_amdgcn_sched_barrier(0);                       \
  } while (0)

// ---------------------------------------------------------------------------
// prep: f16 weight conversion, pair-transposed Whh, bias sums.
// ---------------------------------------------------------------------------
__global__ void prep_kernel(const float* __restrict__ Wih_f, const float* __restrict__ Whh_f,
                            const float* __restrict__ bih_f, const float* __restrict__ bhh_f,
                            const float* __restrict__ Wih_b, const float* __restrict__ Whh_b,
                            const float* __restrict__ bih_b, const float* __restrict__ bhh_b,
                            _Float16* __restrict__ wi16, uint32_t* __restrict__ whT,
                            float* __restrict__ bsum) {
  int i = blockIdx.x * 256 + threadIdx.x;
  if (i < 2 * 512 * 512) {
    const float* s = (i < 512 * 512) ? Wih_f : Wih_b;
    wi16[i] = (_Float16)s[i & (512 * 512 - 1)];
  }
  if (i < 2 * 256 * 512) {
    int d = i >> 17; int rem = i & ((1 << 17) - 1);
    int kp = rem >> 9; int j = rem & 511;
    const float* W = d ? Whh_b : Whh_f;
    h2 p; p[0] = (_Float16)W[j * 512 + 2 * kp]; p[1] = (_Float16)W[j * 512 + 2 * kp + 1];
    whT[i] = __builtin_bit_cast(uint32_t, p);
  }
  if (i < 2 * 512) {
    int d = i >> 9, j = i & 511;
    bsum[i] = d ? (bih_b[j] + bhh_b[j]) : (bih_f[j] + bhh_f[j]);
  }
}

// ---------------------------------------------------------------------------
// xp_gemm (unchanged): xp[dir][m][n] f16, m = b*1024 + t (processing order).
// ---------------------------------------------------------------------------
__global__ __launch_bounds__(256) void xp_gemm(const float* __restrict__ x,
                                               const _Float16* __restrict__ wi,
                                               const float* __restrict__ bsum,
                                               _Float16* __restrict__ xp) {
  __shared__ _Float16 As[128][40];
  __shared__ _Float16 Bs[128][40];
  const int mt = blockIdx.x, nt = blockIdx.y, dir = blockIdx.z;
  const int m0 = mt * 128, n0 = nt * 128;
  const int tid = threadIdx.x;
  const int lane = tid & 63, w = tid >> 6;
  const int wr = w >> 1, wc = w & 1;
  const int ra = tid >> 1, hf = tid & 1;

  const int mrow = m0 + ra;
  const int bb = mrow >> 10, pp = mrow & 1023;
  const int srow = dir ? ((bb << 10) + (1023 - pp)) : mrow;
  const float*    xbase = x + (size_t)srow * 512 + hf * 16;
  const _Float16* wbase = wi + (size_t)dir * 512 * 512 + (size_t)(n0 + ra) * 512 + hf * 16;

  f4 acc[4][4];
  #pragma unroll
  for (int a = 0; a < 4; ++a)
    #pragma unroll
    for (int b = 0; b < 4; ++b) acc[a][b] = (f4)0.f;

  for (int k0 = 0; k0 < 512; k0 += 32) {
    f4 x0 = *(const f4*)(xbase + k0);
    f4 x1 = *(const f4*)(xbase + k0 + 4);
    f4 x2 = *(const f4*)(xbase + k0 + 8);
    f4 x3 = *(const f4*)(xbase + k0 + 12);
    h8 b0 = *(const h8*)(wbase + k0);
    h8 b1 = *(const h8*)(wbase + k0 + 8);
    h8 a0, a1;
    #pragma unroll
    for (int u = 0; u < 4; ++u) {
      a0[u] = (_Float16)x0[u]; a0[4 + u] = (_Float16)x1[u];
      a1[u] = (_Float16)x2[u]; a1[4 + u] = (_Float16)x3[u];
    }
    __syncthreads();
    *(h8*)&As[ra][hf * 16]     = a0;
    *(h8*)&As[ra][hf * 16 + 8] = a1;
    *(h8*)&Bs[ra][hf * 16]     = b0;
    *(h8*)&Bs[ra][hf * 16 + 8] = b1;
    __syncthreads();
    h8 af[4], bf[4];
    #pragma unroll
    for (int fm = 0; fm < 4; ++fm)
      af[fm] = *(const h8*)&As[wr * 64 + fm * 16 + (lane & 15)][(lane >> 4) * 8];
    #pragma unroll
    for (int fn = 0; fn < 4; ++fn)
      bf[fn] = *(const h8*)&Bs[wc * 64 + fn * 16 + (lane & 15)][(lane >> 4) * 8];
    #pragma unroll
    for (int fm = 0; fm < 4; ++fm)
      #pragma unroll
      for (int fn = 0; fn < 4; ++fn)
        acc[fm][fn] = __builtin_amdgcn_mfma_f32_16x16x32_f16(af[fm], bf[fn], acc[fm][fn], 0, 0, 0);
  }

  float bsv[4];
  #pragma unroll
  for (int fn = 0; fn < 4; ++fn)
    bsv[fn] = bsum[dir * 512 + n0 + wc * 64 + fn * 16 + (lane & 15)];
  #pragma unroll
  for (int fm = 0; fm < 4; ++fm)
    #pragma unroll
    for (int fn = 0; fn < 4; ++fn)
      #pragma unroll
      for (int u = 0; u < 4; ++u) {
        int m = m0 + wr * 64 + fm * 16 + (lane >> 4) * 4 + u;
        int n = n0 + wc * 64 + fn * 16 + (lane & 15);
        xp[((size_t)dir << 25) + (size_t)m * 512 + n] = (_Float16)(acc[fm][fn][u] + bsv[fn]);
      }
}

// ---------------------------------------------------------------------------
// rnn_rec (r7): k-eighth waves + conflict-free epilogue.
//   wave w: ke = w>>1 (pairs ke*32..ke*32+31), jh = w&1;
//   lane lv owns j = jh*256 + lv*4 + {0..3}.
//   Weights/lane = 32 pairs x u4: 24 in regs (96 u32, r1/r5-proven no-spill),
//   8 in LDS group-contiguous (b128 reads, conflict-free).
//   h per wave: 8 uniform ds_read_b128 (32 pairs) — HALF of r5's 16.
//   psum[8][512]: one b128 write/lane; B1; epilogue 256 thr x 2 adjacent j:
//   8x ds_read_b64, 2x tanh, pack -> ONE ds_write_b32 (kills the 512/step
//   sub-word write conflicts = the constant 2^26 counter), float2 out store.
// ---------------------------------------------------------------------------
__global__ __launch_bounds__(1024, 4) void rnn_rec(const _Float16* __restrict__ xp,
                                                   const uint32_t* __restrict__ whT,
                                                   float* __restrict__ out) {
  extern __shared__ char smem[];
  uint32_t* wl   = (uint32_t*)smem;              // 128 KB, group-contiguous
  uint32_t* hl   = (uint32_t*)(smem + 131072);   // h(t): 256 f16x2 pairs
  float*    psum = (float*)(smem + 132096);      // [8][512] = 16 KB

  const int bid = blockIdx.x;
  const int dir = bid & 1, b = bid >> 1;
  const int l = threadIdx.x;
  const int w = l >> 6, lv = l & 63;
  const int ke = w >> 1, jh = w & 1;
  const int jbase = jh * 256 + lv * 4;

  // ---- weights: pairs P = ke*32+p, j = jbase..jbase+3 (u4 per pair) ----
  const uint32_t* wb = whT + dir * (256 * 512) + (ke * 32) * 512 + jbase;
  u4 wr_[24];
  #pragma unroll
  for (int p = 0; p < 24; ++p) wr_[p] = *(const u4*)(wb + p * 512);

  // LDS pairs p=24..31: group-contiguous (8-lane groups own 1024 B)
  char* wlb = (char*)wl + (l >> 3) * 1024 + (l & 7) * 16;
  #pragma unroll
  for (int g = 0; g < 8; ++g)
    *(u4*)(wlb + g * 128) = *(const u4*)(wb + (24 + g) * 512);

  if (l < 256) hl[l] = 0;
  __syncthreads();

  const _Float16* xpp = xp + ((size_t)dir << 25) + ((size_t)b << 19);
  float* op = out + (((size_t)(b * 2 + dir)) << 19);

  for (int t = 0; t < TSTEPS; ++t) {
    // xp prefetch for epilogue (2 adjacent f16); never drained at a barrier.
    float xpv0 = 0.f, xpv1 = 0.f;
    if (l < 256) {
      h2 xv = *(const h2*)(xpp + (size_t)t * 512 + 2 * l);
      xpv0 = (float)xv[0]; xpv1 = (float)xv[1];
    }

    f4 acc = (f4)0.f;
    const uint32_t* hq = hl + ke * 32;
    // 24 register pairs (h pairs 0..23 of this k-eighth)
    #pragma unroll
    for (int cb = 0; cb < 6; ++cb) {
      u4 hv = *(const u4*)(hq + cb * 4);          // wave-uniform broadcast
      #pragma unroll
      for (int i = 0; i < 4; ++i) {
        int p = cb * 4 + i;
        #pragma unroll
        for (int jj = 0; jj < 4; ++jj) acc[jj] = fdot2(wr_[p][jj], hv[i], acc[jj]);
      }
    }
    // 8 LDS pairs (h pairs 24..31)
    #pragma unroll
    for (int g2 = 0; g2 < 2; ++g2) {
      u4 hv = *(const u4*)(hq + 24 + g2 * 4);     // wave-uniform broadcast
      #pragma unroll
      for (int i = 0; i < 4; ++i) {
        u4 wv = *(const u4*)(wlb + (g2 * 4 + i) * 128);   // b128, conflict-free
        #pragma unroll
        for (int jj = 0; jj < 4; ++jj) acc[jj] = fdot2(wv[jj], hv[i], acc[jj]);
      }
    }
    *(f4*)(psum + ke * 512 + jbase) = acc;        // one b128 write/lane
    BAR_LDS();                                     // B1 (no vmcnt drain)

    if (l < 256) {
      float s0 = xpv0, s1 = xpv1;
      #pragma unroll
      for (int k2 = 0; k2 < 8; ++k2) {
        f2 v = *(const f2*)(psum + k2 * 512 + 2 * l);     // ds_read_b64
        s0 += v[0]; s1 += v[1];
      }
      float e0 = __expf(2.f * s0);
      float h0 = 1.f - 2.f * __builtin_amdgcn_rcpf(e0 + 1.f);   // tanh(s0)
      float e1 = __expf(2.f * s1);
      float h1 = 1.f - 2.f * __builtin_amdgcn_rcpf(e1 + 1.f);   // tanh(s1)
      f2 o; o[0] = h0; o[1] = h1;
      *(f2*)(op + (size_t)t * 512 + 2 * l) = o;   // coalesced dwordx2 store
      h2 pk; pk[0] = (_Float16)h0; pk[1] = (_Float16)h1;
      hl[l] = __builtin_bit_cast(uint32_t, pk);   // ONE b32 write: no sub-word conflict
    }
    BAR_LDS();                                     // B2: h(t) ready in LDS
  }
}

// ---------------------------------------------------------------------------
extern "C" void kernel_launch(void* const* d_in, const int* in_sizes, int n_in,
                              void* d_out, int out_size, void* d_ws, size_t ws_size,
                              hipStream_t stream) {
  const float* x     = (const float*)d_in[0];
  const float* Wih_f = (const float*)d_in[1];
  const float* Whh_f = (const float*)d_in[2];
  const float* bih_f = (const float*)d_in[3];
  const float* bhh_f = (const float*)d_in[4];
  const float* Wih_b = (const float*)d_in[5];
  const float* Whh_b = (const float*)d_in[6];
  const float* bih_b = (const float*)d_in[7];
  const float* bhh_b = (const float*)d_in[8];

  char* ws = (char*)d_ws;
  _Float16* xp16 = (_Float16*)ws;                 // 128 MB
  _Float16* wi16 = (_Float16*)(ws + 134217728);   // 1 MB
  uint32_t* whT  = (uint32_t*)(ws + 135266304);   // 1 MB
  float*    bsum = (float*)(ws + 136314880);      // 4 KB
  float* out = (float*)d_out;

  prep_kernel<<<2048, 256, 0, stream>>>(Wih_f, Whh_f, bih_f, bhh_f,
                                        Wih_b, Whh_b, bih_b, bhh_b, wi16, whT, bsum);
  dim3 g(512, 4, 2);
  xp_gemm<<<g, 256, 0, stream>>>(x, wi16, bsum, xp16);

  const int REC_LDS = 148480;  // 128K wl + 1K hl + 16K psum
  hipFuncSetAttribute((const void*)rnn_rec, hipFuncAttributeMaxDynamicSharedMemorySize, REC_LDS);
  rnn_rec<<<128, 1024, REC_LDS, stream>>>(xp16, whT, out);
}